// Round 5
// baseline (262.134 us; speedup 1.0000x reference)
//
#include <hip/hip_runtime.h>
#include <cstdint>
#include <cstddef>

#define B_N   16
#define G_N   128
#define FD_N  8192
#define KCH_N 8          // k-split chunks in k_mm
#define KCB   1024       // bf16 elems per chunk (FD_N / KCH_N)
#define BKB   64         // bf16 elems per stage
#define NST   16         // KCB / BKB
#define NROWS 6144       // 3 matrices * 16b * 128 rows

typedef unsigned short u16;
typedef u16  u16x4 __attribute__((ext_vector_type(4)));
typedef u16  u16x8 __attribute__((ext_vector_type(8)));
typedef __bf16 bf16x8 __attribute__((ext_vector_type(8)));
typedef float f32x16 __attribute__((ext_vector_type(16)));

// ---- ws layout (float offsets). Everything written before read; NO zero-init needed.
// Stats are HALF-ROW now: [h2][b*128+row] (k_prep writes, k_fin sums the two halves).
#define QSUM_P   0
#define QSSQ_P   32768
#define KSUM_P   65536
#define KSSQ_P   98304
#define NSSQ_P   131072
#define PART_OFF_F 430080 // u16 region: [256 blk][128][128] bf16 partials (8.4 MB)
#define BF16_OFF_F 2527232 // u16 region: [mat3][b16][row128][8192] bf16 inputs (96 MB)

__device__ __forceinline__ u16 f2bf(float f) {
    uint32_t u = __float_as_uint(f);
    u += 0x7FFFu + ((u >> 16) & 1u);      // RNE
    return (u16)(u >> 16);
}

__device__ __forceinline__ void load_lds16(const float* g, float* l) {
    __builtin_amdgcn_global_load_lds(
        (__attribute__((address_space(1))) void*)(g),
        (__attribute__((address_space(3))) void*)(l),
        16, 0, 0);
}

#define WAITV4() asm volatile("s_waitcnt vmcnt(4)" ::: "memory")
#define WAITV0() asm volatile("s_waitcnt vmcnt(0)" ::: "memory")

// ================= K0: streaming convert fp32->bf16 + half-row stats =========================
// MLP fix vs R4: one wave per HALF-row (12288 waves -> full occupancy), ALL 16 float4 loads
// issued before any use (16 outstanding 16-B loads/lane = 16 KB/wave in flight), 16-B stores.
// Also zeroes out[0] for k_fin's atomics.
__global__ __launch_bounds__(256)
void k_prep(const float* __restrict__ q, const float* __restrict__ kM,
            const float* __restrict__ nM, float* __restrict__ ws,
            float* __restrict__ out)
{
    if (blockIdx.x == 0 && threadIdx.x == 0) out[0] = 0.f;

    const int lane = threadIdx.x & 63;
    const int wv   = threadIdx.x >> 6;
    const int W    = blockIdx.x * 4 + wv;        // 0..12287
    const int R    = W >> 1;                     // global row 0..6143
    const int h    = W & 1;                      // half-row
    const int mat  = R >> 11;                    // 0=q 1=k 2=n
    const int r    = R & 2047;                   // b*128 + row

    const float* src = (mat == 0 ? q : (mat == 1 ? kM : nM))
                       + (size_t)r * FD_N + h * 4096;
    u16* dst = (u16*)(ws + BF16_OFF_F) + (size_t)R * FD_N + h * 4096;

    // lane owns 64 contiguous floats per half-row, walked as 8 iters x 8 floats;
    // wave covers 2 KB contiguous per iter. All 16 float4 loads independent & batched.
    float4 v[16];
    #pragma unroll
    for (int j = 0; j < 8; ++j) {
        const float* p = src + (size_t)j*512 + (size_t)lane*8;
        v[2*j]   = *(const float4*)(p);
        v[2*j+1] = *(const float4*)(p + 4);
    }
    float ss = 0.f, qq = 0.f;
    #pragma unroll
    for (int j = 0; j < 8; ++j) {
        const float4 lo = v[2*j], hi = v[2*j+1];
        ss += (lo.x + lo.y) + (lo.z + lo.w) + (hi.x + hi.y) + (hi.z + hi.w);
        qq += lo.x*lo.x + lo.y*lo.y + lo.z*lo.z + lo.w*lo.w
            + hi.x*hi.x + hi.y*hi.y + hi.z*hi.z + hi.w*hi.w;
        u16x8 hh;
        hh[0]=f2bf(lo.x); hh[1]=f2bf(lo.y); hh[2]=f2bf(lo.z); hh[3]=f2bf(lo.w);
        hh[4]=f2bf(hi.x); hh[5]=f2bf(hi.y); hh[6]=f2bf(hi.z); hh[7]=f2bf(hi.w);
        *(u16x8*)(dst + (size_t)j*512 + (size_t)lane*8) = hh;
    }
    #pragma unroll
    for (int m = 32; m >= 1; m >>= 1) {
        ss += __shfl_xor(ss, m, 64);
        qq += __shfl_xor(qq, m, 64);
    }
    if (lane == 0) {
        const int o = h*2048 + r;
        if (mat == 0)      { ws[QSUM_P + o] = ss; ws[QSSQ_P + o] = qq; }
        else if (mat == 1) { ws[KSUM_P + o] = ss; ws[KSSQ_P + o] = qq; }
        else               { ws[NSSQ_P + o] = qq; }
    }
}

// ================= K1: bf16 GEMM 128x128 tile on the L3-resident bf16 copy ===================
// (unchanged from R4) grid = 16b * 2half * 8kch = 256 x 512. global_load_lds width-16,
// double-buffered, counted vmcnt(4); inverse XOR-swizzle on source, same XOR on ds_read.
__global__ __launch_bounds__(512, 2)
void k_mm(float* __restrict__ ws)
{
    __shared__ __align__(16) u16 sA[2][G_N * BKB];   // 2 x 16 KB
    __shared__ __align__(16) u16 sB[2][G_N * BKB];   // 2 x 16 KB  (64 KB total)

    const int tid = threadIdx.x;
    const int blk = blockIdx.x;       // b*16 + half*8 + kch
    const int b    = blk >> 4;
    const int rem  = blk & 15;
    const int half = rem >> 3;
    const int kch  = rem & 7;

    const int lane  = tid & 63;
    const int wv    = tid >> 6;       // 8 waves
    const int wm    = wv >> 2;        // 0..1 -> 64-row block
    const int wn    = wv & 3;         // 0..3 -> 32-col block
    const int khalf = lane >> 5;
    const int lrow  = lane & 31;
    const int rA0 = wm*64 + lrow;
    const int rB0 = wn*32 + lrow;

    const u16* bf = (const u16*)(ws + BF16_OFF_F);
    const u16* Abase = bf + (size_t)(b*G_N) * FD_N + kch*KCB;
    const u16* Bbase = bf + (size_t)(((half ? 2 : 1)*2048) + b*G_N) * FD_N + kch*KCB;

    const int srow = wv*16 + (lane >> 3);
    const size_t gsw = (size_t)srow * FD_N + (size_t)(((lane & 7) ^ (srow & 7)) << 3);
    const int l0 = wv * 1024;
    const int l1 = l0 + 512;

#define STAGE(ST, T) do {                                                     \
        const size_t tof_ = gsw + (size_t)((T) * BKB);                        \
        load_lds16((const float*)(Abase + tof_),            (float*)(&sA[ST][l0])); \
        load_lds16((const float*)(Bbase + tof_),            (float*)(&sB[ST][l0])); \
        load_lds16((const float*)(Abase + tof_ + 8*FD_N),   (float*)(&sA[ST][l1])); \
        load_lds16((const float*)(Bbase + tof_ + 8*FD_N),   (float*)(&sB[ST][l1])); \
    } while (0)

#define FRAG(SP, R, KC)                                                       \
    __builtin_bit_cast(bf16x8, *(const u16x8*)((SP) + (R)*BKB +               \
        ((((KC)*2 + khalf) ^ ((R)&7)) << 3)))

#define COMPUTE(ST) do {                                                      \
        const u16* dA_ = &sA[ST][0];                                          \
        const u16* dB_ = &sB[ST][0];                                          \
        __builtin_amdgcn_s_setprio(1);                                        \
        _Pragma("unroll")                                                     \
        for (int kc = 0; kc < 4; ++kc) {                                      \
            bf16x8 a0_ = FRAG(dA_, rA0,      kc);                             \
            bf16x8 a1_ = FRAG(dA_, rA0 + 32, kc);                             \
            bf16x8 b0_ = FRAG(dB_, rB0,      kc);                             \
            acc[0] = __builtin_amdgcn_mfma_f32_32x32x16_bf16(a0_, b0_, acc[0], 0,0,0); \
            acc[1] = __builtin_amdgcn_mfma_f32_32x32x16_bf16(a1_, b0_, acc[1], 0,0,0); \
        }                                                                     \
        __builtin_amdgcn_s_setprio(0);                                        \
    } while (0)

    f32x16 acc[2];
    #pragma unroll
    for (int mb = 0; mb < 2; ++mb)
      #pragma unroll
      for (int e = 0; e < 16; ++e) acc[mb][e] = 0.f;

    STAGE(0, 0);
    STAGE(1, 1);

    for (int t = 0; t < NST - 2; t += 2) {
        WAITV4();
        __builtin_amdgcn_s_barrier();
        COMPUTE(0);
        __builtin_amdgcn_s_barrier();
        STAGE(0, t + 2);

        WAITV4();
        __builtin_amdgcn_s_barrier();
        COMPUTE(1);
        __builtin_amdgcn_s_barrier();
        STAGE(1, t + 3);
    }
    WAITV4();
    __builtin_amdgcn_s_barrier();
    COMPUTE(0);
    __builtin_amdgcn_s_barrier();
    WAITV0();
    __builtin_amdgcn_s_barrier();
    COMPUTE(1);

    u16* part = (u16*)(ws + PART_OFF_F) + ((size_t)blk << 14);
    #pragma unroll
    for (int mb = 0; mb < 2; ++mb) {
        const int col = wn*32 + lrow;
        const int rbase = wm*64 + mb*32 + 4*khalf;
        #pragma unroll
        for (int reg = 0; reg < 16; ++reg) {
            const int row = rbase + (reg & 3) + 8*(reg >> 2);
            part[row*G_N + col] = f2bf(acc[mb][reg]);
        }
    }
#undef STAGE
#undef FRAG
#undef COMPUTE
}

// ================= K2: fused reduce + normalize + S-in-LDS + full epilogue ===================
// grid = 16 blocks (one per b) x 1024 thr. S never touches global: built in 64 KB LDS.
// Replaces k_red2 + k_epi (one launch, zero S round-trip).
__global__ __launch_bounds__(1024)
void k_fin(float* __restrict__ ws, float* __restrict__ out)
{
    __shared__ float S_lds[G_N * G_N];                 // 64 KB
    __shared__ float invq[128], nrk[128], nrn[128], sqv[128], skv[128];
    __shared__ float ddq[128], ddk[128], smrow[128], cerow[128];
    __shared__ float wred[16];

    const int b = blockIdx.x;
    const int t = threadIdx.x;
    const float c0 = (float)FD_N * 1e-6f * 1e-6f;

    if (t < 128) {
        const int r = b*G_N + t;
        const float qs = ws[QSUM_P + r] + ws[QSUM_P + 2048 + r];
        const float qq = ws[QSSQ_P + r] + ws[QSSQ_P + 2048 + r];
        const float ks = ws[KSUM_P + r] + ws[KSUM_P + 2048 + r];
        const float kq = ws[KSSQ_P + r] + ws[KSSQ_P + 2048 + r];
        const float nq = ws[NSSQ_P + r] + ws[NSSQ_P + 2048 + r];
        const float iq = 1.f / fmaxf(sqrtf(qq), 1e-12f);
        const float ik = 1.f / fmaxf(sqrtf(kq), 1e-12f);
        invq[t] = iq; nrk[t] = ik;
        nrn[t]  = 1.f / fmaxf(sqrtf(nq), 1e-12f);
        sqv[t]  = qs * iq; skv[t] = ks * ik;
    }
    __syncthreads();

    const int i  = t >> 3;            // 0..127 row
    const int c8 = t & 7;             // 8 threads/row, 16 cols each
    const int j0 = c8 * 16;
    const u16* part = (const u16*)(ws + PART_OFF_F);
    const float iqv = invq[i];

    // ---- half 0 (k): build S in LDS + sm row-part
    {
        float s[16];
        #pragma unroll
        for (int e = 0; e < 16; ++e) s[e] = 0.f;
        #pragma unroll
        for (int kc2 = 0; kc2 < KCH_N; ++kc2) {
            const u16* p = part + (((size_t)(b*16 + kc2)) << 14) + i*G_N + j0;
            const u16x8 h0 = *(const u16x8*)(p);
            const u16x8 h1 = *(const u16x8*)(p + 8);
            #pragma unroll
            for (int e = 0; e < 8; ++e) {
                s[e]   += __uint_as_float(((uint32_t)h0[e]) << 16);
                s[e+8] += __uint_as_float(((uint32_t)h1[e]) << 16);
            }
        }
        float sm = 0.f;
        #pragma unroll
        for (int e = 0; e < 16; ++e) {
            const int j = j0 + e;
            const float Sv = s[e] * iqv * nrk[j];
            S_lds[i*G_N + j] = Sv;
            const float d = Sv - (j == i ? 1.f : 0.f);
            sm += d*d;
        }
        #pragma unroll
        for (int m = 4; m >= 1; m >>= 1) sm += __shfl_xor(sm, m, 64);
        if (c8 == 0) smrow[i] = sm;
    }
    // ---- half 1 (n): CE exp-sum row-part
    {
        float s[16];
        #pragma unroll
        for (int e = 0; e < 16; ++e) s[e] = 0.f;
        #pragma unroll
        for (int kc2 = 0; kc2 < KCH_N; ++kc2) {
            const u16* p = part + (((size_t)(b*16 + 8 + kc2)) << 14) + i*G_N + j0;
            const u16x8 h0 = *(const u16x8*)(p);
            const u16x8 h1 = *(const u16x8*)(p + 8);
            #pragma unroll
            for (int e = 0; e < 8; ++e) {
                s[e]   += __uint_as_float(((uint32_t)h0[e]) << 16);
                s[e+8] += __uint_as_float(((uint32_t)h1[e]) << 16);
            }
        }
        float ea = 0.f;
        #pragma unroll
        for (int e = 0; e < 16; ++e)
            ea += __expf(5.f * s[e] * iqv * nrn[j0 + e]);
        #pragma unroll
        for (int m = 4; m >= 1; m >>= 1) ea += __shfl_xor(ea, m, 64);
        if (c8 == 0) cerow[i] = ea;
    }
    __syncthreads();

    if (t < 128) {
        const float Stt = S_lds[t*G_N + t];
        ddq[t] = sqrtf(fmaxf(2.f - 2.f*Stt + 2e-6f*(sqv[t] - skv[t]) + c0, 0.f));
        ddk[t] = sqrtf(fmaxf(2.f - 2.f*Stt + 2e-6f*(skv[t] - sqv[t]) + c0, 0.f));
    }
    __syncthreads();

    float tri = 0.f, cyc = 0.f, rowterm = 0.f;
    #pragma unroll
    for (int p2 = 0; p2 < 16; ++p2) {
        const int idx = p2*1024 + t;
        const int ii = idx >> 7, jj = idx & 127;
        if (ii != jj) {
            const float S_ij = S_lds[ii*G_N + jj];
            const float dqk = sqrtf(fmaxf(2.f - 2.f*S_ij + 2e-6f*(sqv[ii]-skv[jj]) + c0, 0.f));
            tri += fmaxf(ddq[ii] - dqk + 1.f, 0.f);
            const float dkq = sqrtf(fmaxf(2.f - 2.f*S_ij + 2e-6f*(skv[jj]-sqv[ii]) + c0, 0.f));
            tri += fmaxf(ddk[jj] - dkq + 1.f, 0.f);
            cyc += fabsf(S_ij - S_lds[jj*G_N + ii]);
        }
    }
    if (t < 128) {
        const float lp = 5.f * S_lds[t*G_N + t];
        const float ce = __logf(cerow[t] + __expf(lp)) - lp;
        rowterm = smrow[t] * (1.f/16384.f) + ce * (1.f/16384.f);
    }
    float contrib = rowterm + cyc * (1.f/16256.f)
                  + (float)(B_N - b) * tri * (1.f/32512.f);
    #pragma unroll
    for (int m = 32; m >= 1; m >>= 1) contrib += __shfl_xor(contrib, m, 64);
    if ((t & 63) == 0) wred[t >> 6] = contrib;
    __syncthreads();
    if (t == 0) {
        float tot = 0.f;
        #pragma unroll
        for (int w = 0; w < 16; ++w) tot += wred[w];
        atomicAdd(out, tot);
    }
}

extern "C" void kernel_launch(void* const* d_in, const int* in_sizes, int n_in,
                              void* d_out, int out_size, void* d_ws, size_t ws_size,
                              hipStream_t stream)
{
    const float* q  = (const float*)d_in[0];
    const float* kM = (const float*)d_in[1];
    const float* nM = (const float*)d_in[2];
    float* ws  = (float*)d_ws;
    float* out = (float*)d_out;

    k_prep<<<NROWS*2/4, 256, 0, stream>>>(q, kM, nM, ws, out);
    k_mm<<<256, 512, 0, stream>>>(ws);
    k_fin<<<B_N, 1024, 0, stream>>>(ws, out);
}

// Round 6
// 230.482 us; speedup vs baseline: 1.1373x; 1.1373x over previous
//
#include <hip/hip_runtime.h>
#include <cstdint>
#include <cstddef>

#define B_N   16
#define G_N   128
#define FD_N  8192
#define KSPLIT 16
#define KC    512        // floats per k-chunk
#define BK    64
#define NSTAGE 8         // KC / BK

typedef unsigned short u16;
typedef u16  u16x8 __attribute__((ext_vector_type(8)));
typedef __bf16 bf16x8 __attribute__((ext_vector_type(8)));
typedef float f32x16 __attribute__((ext_vector_type(16)));

// ---- ws layout (float offsets). Everything written before read; NO zero-init needed.
#define QSUM_P   0        // [kch16][b][row]
#define QSSQ_P   32768
#define KSUM_P   65536
#define KSSQ_P   98304
#define NSSQ_P   131072
// u16 region: partials [b2=32][row 128][kch 16][col 128] bf16 = 16.8 MB
#define PART_OFF_F 430080

__device__ __forceinline__ u16 f2bf(float f) {
    uint32_t u = __float_as_uint(f);
    u += 0x7FFFu + ((u >> 16) & 1u);      // RNE
    return (u16)(u >> 16);
}

#define LGKM0_BAR() do { asm volatile("s_waitcnt lgkmcnt(0)" ::: "memory"); \
                         __builtin_amdgcn_s_barrier(); } while (0)

// ================= K1: bf16 GEMM, tile 128 x 256 (cols 0-127 = q.kT, 128-255 = q.nT) =========
// VERBATIM Round-2 kernel (measured 85.6 us, byte-minimal: q/k/n read exactly once = 192 MB,
// which is this platform's ~2.2 TB/s ceiling). grid = 16b * 16kch = 256 blocks x 512 thr.
// Register-staged, bf16 LDS ping-pong (96 KB), XOR-swizzled 8B units, stats at stage time.
// Only change: zeroes out[0] for k_fin's atomics.
__global__ __launch_bounds__(512, 2)
void k_gemm(const float* __restrict__ q, const float* __restrict__ kM,
            const float* __restrict__ nM, float* __restrict__ ws,
            float* __restrict__ out)
{
    __shared__ __align__(16) u16 smem[2 * 24576];   // [buf][A 8192 | B 16384] u16 = 96 KB

    const int tid = threadIdx.x;
    const int blk = blockIdx.x;       // b*16 + kch
    const int b   = blk >> 4;
    const int kch = blk & 15;

    if (blk == 0 && tid == 0) out[0] = 0.f;

    const int lane  = tid & 63;
    const int wv    = tid >> 6;       // 8 waves
    const int wm    = wv >> 2;        // 0..1 -> 64-row block
    const int wn    = wv & 3;         // 0..3 -> 64-col block
    const int khalf = lane >> 5;
    const int lrow  = lane & 31;
    const int g     = lane >> 4;      // 0..3  (row-within-quad for staging)
    const int cc    = lane & 15;      // 0..15 (16B slot within 256B burst)

    const size_t mat_off = (size_t)b * (G_N * FD_N) + (size_t)kch * KC;
    const float* Ap = q + mat_off;
    const float* Bw = (wv < 4 ? kM : nM) + mat_off;   // waves 0-3 stage k, 4-7 stage n

    float4 La[4], Lb[8];
    float sA_[4] = {0,0,0,0}, qA_[4] = {0,0,0,0};
    float sB_[8] = {0,0,0,0,0,0,0,0}, qB_[8] = {0,0,0,0,0,0,0,0};

    f32x16 acc[2][2];
    #pragma unroll
    for (int m = 0; m < 2; ++m)
      #pragma unroll
      for (int n = 0; n < 2; ++n)
        #pragma unroll
        for (int e = 0; e < 16; ++e) acc[m][n][e] = 0.f;

#define ISSUE(S) do {                                                          \
        const size_t ko_ = (size_t)((S)*BK + cc*4);                            \
        _Pragma("unroll")                                                      \
        for (int i = 0; i < 4; ++i)                                            \
            La[i] = *(const float4*)(Ap + (size_t)(wv*16 + i*4 + g)*FD_N + ko_); \
        _Pragma("unroll")                                                      \
        for (int i = 0; i < 8; ++i)                                            \
            Lb[i] = *(const float4*)(Bw + (size_t)(wn*32 + i*4 + g)*FD_N + ko_); \
    } while (0)

#define CVTWRITE(BUF) do {                                                     \
        u16* dA_ = smem + (BUF)*24576;                                         \
        u16* dB_ = dA_ + 8192;                                                 \
        _Pragma("unroll")                                                      \
        for (int i = 0; i < 4; ++i) {                                          \
            const int r_ = wv*16 + i*4 + g;                                    \
            float4 v = La[i];                                                  \
            sA_[i] += (v.x + v.y) + (v.z + v.w);                               \
            qA_[i] += v.x*v.x + v.y*v.y + v.z*v.z + v.w*v.w;                   \
            uint2 p;                                                           \
            p.x = (uint32_t)f2bf(v.x) | ((uint32_t)f2bf(v.y) << 16);           \
            p.y = (uint32_t)f2bf(v.z) | ((uint32_t)f2bf(v.w) << 16);           \
            *(uint2*)(dA_ + r_*64 + ((cc ^ ((r_&7)<<1)) << 2)) = p;            \
        }                                                                      \
        _Pragma("unroll")                                                      \
        for (int i = 0; i < 8; ++i) {                                          \
            const int r_  = wn*32 + i*4 + g;                                   \
            const int rl_ = r_ + (wv < 4 ? 0 : 128);                           \
            float4 v = Lb[i];                                                  \
            sB_[i] += (v.x + v.y) + (v.z + v.w);                               \
            qB_[i] += v.x*v.x + v.y*v.y + v.z*v.z + v.w*v.w;                   \
            uint2 p;                                                           \
            p.x = (uint32_t)f2bf(v.x) | ((uint32_t)f2bf(v.y) << 16);           \
            p.y = (uint32_t)f2bf(v.z) | ((uint32_t)f2bf(v.w) << 16);           \
            *(uint2*)(dB_ + rl_*64 + ((cc ^ ((rl_&7)<<1)) << 2)) = p;          \
        }                                                                      \
    } while (0)

#define FRAG(DP, R, KCH)                                                       \
    __builtin_bit_cast(bf16x8, *(const u16x8*)((DP) + (R)*64 +                 \
        ((((KCH)*2 + khalf) ^ ((R)&7)) << 3)))

#define COMPUTE(BUF) do {                                                      \
        const u16* dA_ = smem + (BUF)*24576;                                   \
        const u16* dB_ = dA_ + 8192;                                           \
        __builtin_amdgcn_s_setprio(1);                                         \
        _Pragma("unroll")                                                      \
        for (int kc = 0; kc < 4; ++kc) {                                       \
            bf16x8 a0_ = FRAG(dA_, wm*64 +      lrow, kc);                     \
            bf16x8 a1_ = FRAG(dA_, wm*64 + 32 + lrow, kc);                     \
            bf16x8 b0_ = FRAG(dB_, wn*64 +      lrow, kc);                     \
            bf16x8 b1_ = FRAG(dB_, wn*64 + 32 + lrow, kc);                     \
            acc[0][0] = __builtin_amdgcn_mfma_f32_32x32x16_bf16(a0_, b0_, acc[0][0], 0,0,0); \
            acc[0][1] = __builtin_amdgcn_mfma_f32_32x32x16_bf16(a0_, b1_, acc[0][1], 0,0,0); \
            acc[1][0] = __builtin_amdgcn_mfma_f32_32x32x16_bf16(a1_, b0_, acc[1][0], 0,0,0); \
            acc[1][1] = __builtin_amdgcn_mfma_f32_32x32x16_bf16(a1_, b1_, acc[1][1], 0,0,0); \
        }                                                                      \
        __builtin_amdgcn_s_setprio(0);                                         \
    } while (0)

    // prologue: stage 0 (exposed fill)
    ISSUE(0);
    CVTWRITE(0);
    LGKM0_BAR();

    // steady state: next stage's loads fly across the whole MFMA phase.
    for (int s = 0; s < NSTAGE; ++s) {
        if (s + 1 < NSTAGE) ISSUE(s + 1);
        COMPUTE(s & 1);
        if (s + 1 < NSTAGE) {
            LGKM0_BAR();
            CVTWRITE((s + 1) & 1);
            LGKM0_BAR();
        }
    }

    // ---- C write: layout [b2][row][kch16][col] bf16; C/D map col=lane&31,
    // row=(reg&3)+8*(reg>>2)+4*khalf
    u16* part = (u16*)(ws + PART_OFF_F);
    #pragma unroll
    for (int m = 0; m < 2; ++m)
      #pragma unroll
      for (int n = 0; n < 2; ++n) {
        const int colg = wn*64 + n*32 + lrow;     // 0..255
        const int ho   = colg >> 7;               // 0: k-half, 1: n-half
        const int col  = colg & 127;
        u16* pb = part + (size_t)(b*2 + ho) * 262144;
        const int rbase = wm*64 + m*32 + 4*khalf;
        #pragma unroll
        for (int reg = 0; reg < 16; ++reg) {
            const int row = rbase + (reg & 3) + 8*(reg >> 2);
            pb[(row*16 + kch)*128 + col] = f2bf(acc[m][n][reg]);
        }
      }

    // ---- per-chunk row stats: reduce over the 16 lanes (cc) sharing each row
    #pragma unroll
    for (int i = 0; i < 4; ++i)
        #pragma unroll
        for (int msk = 8; msk >= 1; msk >>= 1) {
            sA_[i] += __shfl_xor(sA_[i], msk, 64);
            qA_[i] += __shfl_xor(qA_[i], msk, 64);
        }
    #pragma unroll
    for (int i = 0; i < 8; ++i)
        #pragma unroll
        for (int msk = 8; msk >= 1; msk >>= 1) {
            sB_[i] += __shfl_xor(sB_[i], msk, 64);
            qB_[i] += __shfl_xor(qB_[i], msk, 64);
        }
    if (cc == 0) {
        #pragma unroll
        for (int i = 0; i < 4; ++i) {
            const int o = kch*2048 + b*G_N + (wv*16 + i*4 + g);
            ws[QSUM_P + o] = sA_[i]; ws[QSSQ_P + o] = qA_[i];
        }
        #pragma unroll
        for (int i = 0; i < 8; ++i) {
            const int o = kch*2048 + b*G_N + (wn*32 + i*4 + g);
            if (wv < 4) { ws[KSUM_P + o] = sB_[i]; ws[KSSQ_P + o] = qB_[i]; }
            else        { ws[NSSQ_P + o] = qB_[i]; }
        }
    }
#undef ISSUE
#undef CVTWRITE
#undef FRAG
#undef COMPUTE
}

// ================= K2: fused reduce + normalize + S-in-LDS + full epilogue ===================
// grid = 16 blocks (one per b) x 1024 thr. S never touches global: built in 64 KB LDS.
// Structure proven in R5 (passed); adapted to 16-chunk stats and [b2][row][kch16][col] partials.
__global__ __launch_bounds__(1024)
void k_fin(float* __restrict__ ws, float* __restrict__ out)
{
    __shared__ float S_lds[G_N * G_N];                 // 64 KB
    __shared__ float invq[128], nrk[128], nrn[128], sqv[128], skv[128];
    __shared__ float ddq[128], ddk[128], smrow[128], cerow[128];
    __shared__ float wred[16];

    const int b = blockIdx.x;
    const int t = threadIdx.x;
    const float c0 = (float)FD_N * 1e-6f * 1e-6f;

    if (t < 128) {
        float qs=0.f, qq=0.f, ks=0.f, kq=0.f, nq=0.f;
        #pragma unroll
        for (int kc = 0; kc < KSPLIT; ++kc) {
            const int o = kc*2048 + b*G_N + t;
            qs += ws[QSUM_P + o]; qq += ws[QSSQ_P + o];
            ks += ws[KSUM_P + o]; kq += ws[KSSQ_P + o];
            nq += ws[NSSQ_P + o];
        }
        const float iq = 1.f / fmaxf(sqrtf(qq), 1e-12f);
        const float ik = 1.f / fmaxf(sqrtf(kq), 1e-12f);
        invq[t] = iq; nrk[t] = ik;
        nrn[t]  = 1.f / fmaxf(sqrtf(nq), 1e-12f);
        sqv[t]  = qs * iq; skv[t] = ks * ik;
    }
    __syncthreads();

    const int i  = t >> 3;            // 0..127 row
    const int c8 = t & 7;             // 8 threads/row, 16 cols each
    const int j0 = c8 * 16;
    const u16* part = (const u16*)(ws + PART_OFF_F);
    const float iqv = invq[i];

    // ---- half 0 (k): build S in LDS + sm row-part. Row's 16 chunks are 4 KB contiguous.
    {
        float s[16];
        #pragma unroll
        for (int e = 0; e < 16; ++e) s[e] = 0.f;
        const u16* p0 = part + (size_t)(b*2) * 262144 + i*2048 + j0;
        #pragma unroll
        for (int kc = 0; kc < KSPLIT; ++kc) {
            const u16x8 h0 = *(const u16x8*)(p0 + kc*128);
            const u16x8 h1 = *(const u16x8*)(p0 + kc*128 + 8);
            #pragma unroll
            for (int e = 0; e < 8; ++e) {
                s[e]   += __uint_as_float(((uint32_t)h0[e]) << 16);
                s[e+8] += __uint_as_float(((uint32_t)h1[e]) << 16);
            }
        }
        float sm = 0.f;
        #pragma unroll
        for (int e = 0; e < 16; ++e) {
            const int j = j0 + e;
            const float Sv = s[e] * iqv * nrk[j];
            S_lds[i*G_N + j] = Sv;
            const float d = Sv - (j == i ? 1.f : 0.f);
            sm += d*d;
        }
        #pragma unroll
        for (int m = 4; m >= 1; m >>= 1) sm += __shfl_xor(sm, m, 64);
        if (c8 == 0) smrow[i] = sm;
    }
    // ---- half 1 (n): CE exp-sum row-part
    {
        float s[16];
        #pragma unroll
        for (int e = 0; e < 16; ++e) s[e] = 0.f;
        const u16* p1 = part + (size_t)(b*2 + 1) * 262144 + i*2048 + j0;
        #pragma unroll
        for (int kc = 0; kc < KSPLIT; ++kc) {
            const u16x8 h0 = *(const u16x8*)(p1 + kc*128);
            const u16x8 h1 = *(const u16x8*)(p1 + kc*128 + 8);
            #pragma unroll
            for (int e = 0; e < 8; ++e) {
                s[e]   += __uint_as_float(((uint32_t)h0[e]) << 16);
                s[e+8] += __uint_as_float(((uint32_t)h1[e]) << 16);
            }
        }
        float ea = 0.f;
        #pragma unroll
        for (int e = 0; e < 16; ++e)
            ea += __expf(5.f * s[e] * iqv * nrn[j0 + e]);
        #pragma unroll
        for (int m = 4; m >= 1; m >>= 1) ea += __shfl_xor(ea, m, 64);
        if (c8 == 0) cerow[i] = ea;
    }
    __syncthreads();

    if (t < 128) {
        const float Stt = S_lds[t*G_N + t];
        ddq[t] = sqrtf(fmaxf(2.f - 2.f*Stt + 2e-6f*(sqv[t] - skv[t]) + c0, 0.f));
        ddk[t] = sqrtf(fmaxf(2.f - 2.f*Stt + 2e-6f*(skv[t] - sqv[t]) + c0, 0.f));
    }
    __syncthreads();

    float tri = 0.f, cyc = 0.f, rowterm = 0.f;
    #pragma unroll
    for (int p2 = 0; p2 < 16; ++p2) {
        const int idx = p2*1024 + t;
        const int ii = idx >> 7, jj = idx & 127;
        if (ii != jj) {
            const float S_ij = S_lds[ii*G_N + jj];
            const float dqk = sqrtf(fmaxf(2.f - 2.f*S_ij + 2e-6f*(sqv[ii]-skv[jj]) + c0, 0.f));
            tri += fmaxf(ddq[ii] - dqk + 1.f, 0.f);
            const float dkq = sqrtf(fmaxf(2.f - 2.f*S_ij + 2e-6f*(skv[jj]-sqv[ii]) + c0, 0.f));
            tri += fmaxf(ddk[jj] - dkq + 1.f, 0.f);
            cyc += fabsf(S_ij - S_lds[jj*G_N + ii]);
        }
    }
    if (t < 128) {
        const float lp = 5.f * S_lds[t*G_N + t];
        const float ce = __logf(cerow[t] + __expf(lp)) - lp;
        rowterm = smrow[t] * (1.f/16384.f) + ce * (1.f/16384.f);
    }
    float contrib = rowterm + cyc * (1.f/16256.f)
                  + (float)(B_N - b) * tri * (1.f/32512.f);
    #pragma unroll
    for (int m = 32; m >= 1; m >>= 1) contrib += __shfl_xor(contrib, m, 64);
    if ((t & 63) == 0) wred[t >> 6] = contrib;
    __syncthreads();
    if (t == 0) {
        float tot = 0.f;
        #pragma unroll
        for (int w = 0; w < 16; ++w) tot += wred[w];
        atomicAdd(out, tot);
    }
}

extern "C" void kernel_launch(void* const* d_in, const int* in_sizes, int n_in,
                              void* d_out, int out_size, void* d_ws, size_t ws_size,
                              hipStream_t stream)
{
    const float* q  = (const float*)d_in[0];
    const float* kM = (const float*)d_in[1];
    const float* nM = (const float*)d_in[2];
    float* ws  = (float*)d_ws;
    float* out = (float*)d_out;

    k_gemm<<<B_N * KSPLIT, 512, 0, stream>>>(q, kM, nM, ws, out);
    k_fin<<<B_N, 1024, 0, stream>>>(ws, out);
}

// Round 7
// 221.593 us; speedup vs baseline: 1.1830x; 1.0401x over previous
//
#include <hip/hip_runtime.h>
#include <cstdint>
#include <cstddef>

#define B_N   16
#define G_N   128
#define FD_N  8192
#define KSPLIT 16
#define KC    512        // floats per k-chunk
#define BK    64
#define NSTAGE 8         // KC / BK

typedef unsigned short u16;
typedef u16  u16x4 __attribute__((ext_vector_type(4)));
typedef u16  u16x8 __attribute__((ext_vector_type(8)));
typedef __bf16 bf16x8 __attribute__((ext_vector_type(8)));
typedef float f32x16 __attribute__((ext_vector_type(16)));

// ---- ws layout (float offsets). Everything written before read; NO zero-init needed.
#define QSUM_P   0        // [kch16][b][row]
#define QSSQ_P   32768
#define KSUM_P   65536
#define KSSQ_P   98304
#define NSSQ_P   131072
// u16 region: partials [b2=32][row 128][kch 16][col 128] bf16 = 16.8 MB
#define PART_OFF_F 430080

__device__ __forceinline__ u16 f2bf(float f) {
    uint32_t u = __float_as_uint(f);
    u += 0x7FFFu + ((u >> 16) & 1u);      // RNE
    return (u16)(u >> 16);
}
__device__ __forceinline__ float bf2f(u16 h) {
    return __uint_as_float(((uint32_t)h) << 16);
}

#define LGKM0_BAR() do { asm volatile("s_waitcnt lgkmcnt(0)" ::: "memory"); \
                         __builtin_amdgcn_s_barrier(); } while (0)

// ================= K1: bf16 GEMM, tile 128 x 256 (cols 0-127 = q.kT, 128-255 = q.nT) =========
// VERBATIM proven kernel (86-87 us, byte-minimal: q/k/n read exactly once = 192 MB = this
// platform's ~2.4 TB/s request ceiling). grid = 16b * 16kch = 256 blocks x 512 thr.
__global__ __launch_bounds__(512, 2)
void k_gemm(const float* __restrict__ q, const float* __restrict__ kM,
            const float* __restrict__ nM, float* __restrict__ ws,
            float* __restrict__ out)
{
    __shared__ __align__(16) u16 smem[2 * 24576];   // [buf][A 8192 | B 16384] u16 = 96 KB

    const int tid = threadIdx.x;
    const int blk = blockIdx.x;       // b*16 + kch
    const int b   = blk >> 4;
    const int kch = blk & 15;

    if (blk == 0 && tid == 0) out[0] = 0.f;

    const int lane  = tid & 63;
    const int wv    = tid >> 6;       // 8 waves
    const int wm    = wv >> 2;        // 0..1 -> 64-row block
    const int wn    = wv & 3;         // 0..3 -> 64-col block
    const int khalf = lane >> 5;
    const int lrow  = lane & 31;
    const int g     = lane >> 4;      // 0..3  (row-within-quad for staging)
    const int cc    = lane & 15;      // 0..15 (16B slot within 256B burst)

    const size_t mat_off = (size_t)b * (G_N * FD_N) + (size_t)kch * KC;
    const float* Ap = q + mat_off;
    const float* Bw = (wv < 4 ? kM : nM) + mat_off;   // waves 0-3 stage k, 4-7 stage n

    float4 La[4], Lb[8];
    float sA_[4] = {0,0,0,0}, qA_[4] = {0,0,0,0};
    float sB_[8] = {0,0,0,0,0,0,0,0}, qB_[8] = {0,0,0,0,0,0,0,0};

    f32x16 acc[2][2];
    #pragma unroll
    for (int m = 0; m < 2; ++m)
      #pragma unroll
      for (int n = 0; n < 2; ++n)
        #pragma unroll
        for (int e = 0; e < 16; ++e) acc[m][n][e] = 0.f;

#define ISSUE(S) do {                                                          \
        const size_t ko_ = (size_t)((S)*BK + cc*4);                            \
        _Pragma("unroll")                                                      \
        for (int i = 0; i < 4; ++i)                                            \
            La[i] = *(const float4*)(Ap + (size_t)(wv*16 + i*4 + g)*FD_N + ko_); \
        _Pragma("unroll")                                                      \
        for (int i = 0; i < 8; ++i)                                            \
            Lb[i] = *(const float4*)(Bw + (size_t)(wn*32 + i*4 + g)*FD_N + ko_); \
    } while (0)

#define CVTWRITE(BUF) do {                                                     \
        u16* dA_ = smem + (BUF)*24576;                                         \
        u16* dB_ = dA_ + 8192;                                                 \
        _Pragma("unroll")                                                      \
        for (int i = 0; i < 4; ++i) {                                          \
            const int r_ = wv*16 + i*4 + g;                                    \
            float4 v = La[i];                                                  \
            sA_[i] += (v.x + v.y) + (v.z + v.w);                               \
            qA_[i] += v.x*v.x + v.y*v.y + v.z*v.z + v.w*v.w;                   \
            uint2 p;                                                           \
            p.x = (uint32_t)f2bf(v.x) | ((uint32_t)f2bf(v.y) << 16);           \
            p.y = (uint32_t)f2bf(v.z) | ((uint32_t)f2bf(v.w) << 16);           \
            *(uint2*)(dA_ + r_*64 + ((cc ^ ((r_&7)<<1)) << 2)) = p;            \
        }                                                                      \
        _Pragma("unroll")                                                      \
        for (int i = 0; i < 8; ++i) {                                          \
            const int r_  = wn*32 + i*4 + g;                                   \
            const int rl_ = r_ + (wv < 4 ? 0 : 128);                           \
            float4 v = Lb[i];                                                  \
            sB_[i] += (v.x + v.y) + (v.z + v.w);                               \
            qB_[i] += v.x*v.x + v.y*v.y + v.z*v.z + v.w*v.w;                   \
            uint2 p;                                                           \
            p.x = (uint32_t)f2bf(v.x) | ((uint32_t)f2bf(v.y) << 16);           \
            p.y = (uint32_t)f2bf(v.z) | ((uint32_t)f2bf(v.w) << 16);           \
            *(uint2*)(dB_ + rl_*64 + ((cc ^ ((rl_&7)<<1)) << 2)) = p;          \
        }                                                                      \
    } while (0)

#define FRAG(DP, R, KCH)                                                       \
    __builtin_bit_cast(bf16x8, *(const u16x8*)((DP) + (R)*64 +                 \
        ((((KCH)*2 + khalf) ^ ((R)&7)) << 3)))

#define COMPUTE(BUF) do {                                                      \
        const u16* dA_ = smem + (BUF)*24576;                                   \
        const u16* dB_ = dA_ + 8192;                                           \
        __builtin_amdgcn_s_setprio(1);                                         \
        _Pragma("unroll")                                                      \
        for (int kc = 0; kc < 4; ++kc) {                                       \
            bf16x8 a0_ = FRAG(dA_, wm*64 +      lrow, kc);                     \
            bf16x8 a1_ = FRAG(dA_, wm*64 + 32 + lrow, kc);                     \
            bf16x8 b0_ = FRAG(dB_, wn*64 +      lrow, kc);                     \
            bf16x8 b1_ = FRAG(dB_, wn*64 + 32 + lrow, kc);                     \
            acc[0][0] = __builtin_amdgcn_mfma_f32_32x32x16_bf16(a0_, b0_, acc[0][0], 0,0,0); \
            acc[0][1] = __builtin_amdgcn_mfma_f32_32x32x16_bf16(a0_, b1_, acc[0][1], 0,0,0); \
            acc[1][0] = __builtin_amdgcn_mfma_f32_32x32x16_bf16(a1_, b0_, acc[1][0], 0,0,0); \
            acc[1][1] = __builtin_amdgcn_mfma_f32_32x32x16_bf16(a1_, b1_, acc[1][1], 0,0,0); \
        }                                                                      \
        __builtin_amdgcn_s_setprio(0);                                         \
    } while (0)

    ISSUE(0);
    CVTWRITE(0);
    LGKM0_BAR();

    for (int s = 0; s < NSTAGE; ++s) {
        if (s + 1 < NSTAGE) ISSUE(s + 1);
        COMPUTE(s & 1);
        if (s + 1 < NSTAGE) {
            LGKM0_BAR();
            CVTWRITE((s + 1) & 1);
            LGKM0_BAR();
        }
    }

    // ---- C write: layout [b2][row][kch16][col] bf16
    u16* part = (u16*)(ws + PART_OFF_F);
    #pragma unroll
    for (int m = 0; m < 2; ++m)
      #pragma unroll
      for (int n = 0; n < 2; ++n) {
        const int colg = wn*64 + n*32 + lrow;     // 0..255
        const int ho   = colg >> 7;               // 0: k-half, 1: n-half
        const int col  = colg & 127;
        u16* pb = part + (size_t)(b*2 + ho) * 262144;
        const int rbase = wm*64 + m*32 + 4*khalf;
        #pragma unroll
        for (int reg = 0; reg < 16; ++reg) {
            const int row = rbase + (reg & 3) + 8*(reg >> 2);
            pb[(row*16 + kch)*128 + col] = f2bf(acc[m][n][reg]);
        }
      }

    // ---- per-chunk row stats
    #pragma unroll
    for (int i = 0; i < 4; ++i)
        #pragma unroll
        for (int msk = 8; msk >= 1; msk >>= 1) {
            sA_[i] += __shfl_xor(sA_[i], msk, 64);
            qA_[i] += __shfl_xor(qA_[i], msk, 64);
        }
    #pragma unroll
    for (int i = 0; i < 8; ++i)
        #pragma unroll
        for (int msk = 8; msk >= 1; msk >>= 1) {
            sB_[i] += __shfl_xor(sB_[i], msk, 64);
            qB_[i] += __shfl_xor(qB_[i], msk, 64);
        }
    if (cc == 0) {
        #pragma unroll
        for (int i = 0; i < 4; ++i) {
            const int o = kch*2048 + b*G_N + (wv*16 + i*4 + g);
            ws[QSUM_P + o] = sA_[i]; ws[QSSQ_P + o] = qA_[i];
        }
        #pragma unroll
        for (int i = 0; i < 8; ++i) {
            const int o = kch*2048 + b*G_N + (wn*32 + i*4 + g);
            if (wv < 4) { ws[KSUM_P + o] = sB_[i]; ws[KSSQ_P + o] = qB_[i]; }
            else        { ws[NSSQ_P + o] = qB_[i]; }
        }
    }
#undef ISSUE
#undef CVTWRITE
#undef FRAG
#undef COMPUTE
}

// ================= K2: WIDE fused epilogue — 128 blocks (b x 16-row group) x 512 thr =========
// Each block: full-row stats; own-row S (both halves) from partials; TRANSPOSED S[j, own-cols]
// + full diagonal reduced directly from partials (no global S ever); tri/cyc/ce; atomicAdd.
__global__ __launch_bounds__(512)
void k_fin2(float* __restrict__ ws, float* __restrict__ out)
{
    __shared__ float invq[128], nrk[128], nrn[128], sqv[128], skv[128], diagv[128], ddk[128];
    __shared__ float Sown[16][128];      // own-row S, half0 (8 KB)
    __shared__ float Scol[128][17];      // S[j][own-col], padded (8.7 KB)
    __shared__ float smrow[16], cerow[16], ddqv[16], cev[16];
    __shared__ float wred[8];

    const int blk = blockIdx.x;          // b*8 + rg
    const int b   = blk >> 3;
    const int i0  = (blk & 7) * 16;
    const int t   = threadIdx.x;
    const float c0 = (float)FD_N * 1e-6f * 1e-6f;
    const u16* pb0 = (const u16*)(ws + PART_OFF_F) + (size_t)(b*2) * 262144;
    const u16* pb1 = pb0 + 262144;

    // ---- phase 0: full-row stats for all 128 rows of this b (4 threads/row, 4 chunks each)
    {
        const int r = t >> 2, p = t & 3;
        float qs=0.f, qq=0.f, ks=0.f, kq=0.f, nq=0.f;
        #pragma unroll
        for (int e = 0; e < 4; ++e) {
            const int o = (p*4 + e)*2048 + b*G_N + r;
            qs += ws[QSUM_P + o]; qq += ws[QSSQ_P + o];
            ks += ws[KSUM_P + o]; kq += ws[KSSQ_P + o];
            nq += ws[NSSQ_P + o];
        }
        #pragma unroll
        for (int m = 1; m <= 2; m <<= 1) {
            qs += __shfl_xor(qs, m, 64); qq += __shfl_xor(qq, m, 64);
            ks += __shfl_xor(ks, m, 64); kq += __shfl_xor(kq, m, 64);
            nq += __shfl_xor(nq, m, 64);
        }
        if (p == 0) {
            const float iq = 1.f / fmaxf(sqrtf(qq), 1e-12f);
            const float ik = 1.f / fmaxf(sqrtf(kq), 1e-12f);
            invq[r] = iq; nrk[r] = ik;
            nrn[r]  = 1.f / fmaxf(sqrtf(nq), 1e-12f);
            sqv[r]  = qs * iq; skv[r] = ks * ik;
        }
    }
    __syncthreads();

    const int il  = t >> 5;        // 0..15 own row
    const int ct  = t & 31;        // 32 col-threads/row
    const int i   = i0 + il;
    const int c0i = ct * 4;
    const float iqv = invq[i];

    // ---- phase 1a: own-row S (half 0, k) + sm row part. Row's chunks 4 KB contiguous.
    {
        float s0=0.f, s1=0.f, s2=0.f, s3=0.f;
        const u16* p = pb0 + (size_t)(i*16)*128 + c0i;
        #pragma unroll
        for (int kc = 0; kc < 16; ++kc) {
            const u16x4 h = *(const u16x4*)(p + kc*128);
            s0 += bf2f(h[0]); s1 += bf2f(h[1]); s2 += bf2f(h[2]); s3 += bf2f(h[3]);
        }
        float4 Sv;
        Sv.x = s0 * iqv * nrk[c0i];     Sv.y = s1 * iqv * nrk[c0i+1];
        Sv.z = s2 * iqv * nrk[c0i+2];   Sv.w = s3 * iqv * nrk[c0i+3];
        *(float4*)&Sown[il][c0i] = Sv;
        float sm = 0.f;
        {
            float d = Sv.x - (c0i   == i ? 1.f : 0.f); sm += d*d;
            d = Sv.y - (c0i+1 == i ? 1.f : 0.f); sm += d*d;
            d = Sv.z - (c0i+2 == i ? 1.f : 0.f); sm += d*d;
            d = Sv.w - (c0i+3 == i ? 1.f : 0.f); sm += d*d;
        }
        #pragma unroll
        for (int m = 16; m >= 1; m >>= 1) sm += __shfl_xor(sm, m, 64);
        if (ct == 0) smrow[il] = sm;
    }
    // ---- phase 1b: half 1 (n) -> CE exp-sum row part
    {
        float s0=0.f, s1=0.f, s2=0.f, s3=0.f;
        const u16* p = pb1 + (size_t)(i*16)*128 + c0i;
        #pragma unroll
        for (int kc = 0; kc < 16; ++kc) {
            const u16x4 h = *(const u16x4*)(p + kc*128);
            s0 += bf2f(h[0]); s1 += bf2f(h[1]); s2 += bf2f(h[2]); s3 += bf2f(h[3]);
        }
        float ea = __expf(5.f * s0 * iqv * nrn[c0i])
                 + __expf(5.f * s1 * iqv * nrn[c0i+1])
                 + __expf(5.f * s2 * iqv * nrn[c0i+2])
                 + __expf(5.f * s3 * iqv * nrn[c0i+3]);
        #pragma unroll
        for (int m = 16; m >= 1; m >>= 1) ea += __shfl_xor(ea, m, 64);
        if (ct == 0) cerow[il] = ea;
    }

    // ---- phase 2: transposed entries S[j][own cols] + full diagonal (4 threads/j)
    {
        const int j = t >> 2, p = t & 3;
        float cs[16];
        #pragma unroll
        for (int e = 0; e < 16; ++e) cs[e] = 0.f;
        float dg = 0.f;
        #pragma unroll
        for (int e2 = 0; e2 < 4; ++e2) {
            const int kc = p*4 + e2;
            const u16* pp = pb0 + (size_t)(j*16 + kc)*128;
            const u16x8 h0 = *(const u16x8*)(pp + i0);
            const u16x8 h1 = *(const u16x8*)(pp + i0 + 8);
            #pragma unroll
            for (int e = 0; e < 8; ++e) {
                cs[e]   += bf2f(h0[e]);
                cs[e+8] += bf2f(h1[e]);
            }
            dg += bf2f(pp[j]);
        }
        #pragma unroll
        for (int m = 1; m <= 2; m <<= 1) {
            #pragma unroll
            for (int e = 0; e < 16; ++e) cs[e] += __shfl_xor(cs[e], m, 64);
            dg += __shfl_xor(dg, m, 64);
        }
        if (p == 0) {
            const float sj = invq[j];
            #pragma unroll
            for (int e = 0; e < 16; ++e)
                Scol[j][e] = cs[e] * sj * nrk[i0 + e];
            diagv[j] = dg * sj * nrk[j];
        }
    }
    __syncthreads();

    // ---- phase 2b: ddk (all j), ddq + ce (own rows)
    if (t < 128) {
        ddk[t] = sqrtf(fmaxf(2.f - 2.f*diagv[t] + 2e-6f*(skv[t] - sqv[t]) + c0, 0.f));
    } else if (t < 144) {
        const int r = i0 + (t - 128);
        ddqv[t-128] = sqrtf(fmaxf(2.f - 2.f*diagv[r] + 2e-6f*(sqv[r] - skv[r]) + c0, 0.f));
    } else if (t < 160) {
        const int r  = i0 + (t - 144);
        const float lp = 5.f * diagv[r];
        cev[t-144] = __logf(cerow[t-144] + __expf(lp)) - lp;
    }
    __syncthreads();

    // ---- phase 3: tri / cyc over own rows x all j
    float tri = 0.f, cyc = 0.f;
    #pragma unroll
    for (int e = 0; e < 4; ++e) {
        const int j = c0i + e;
        if (j != i) {
            const float Sij = Sown[il][j];
            const float dqk = sqrtf(fmaxf(2.f - 2.f*Sij + 2e-6f*(sqv[i] - skv[j]) + c0, 0.f));
            tri += fmaxf(ddqv[il] - dqk + 1.f, 0.f);
            const float dkq = sqrtf(fmaxf(2.f - 2.f*Sij + 2e-6f*(skv[j] - sqv[i]) + c0, 0.f));
            tri += fmaxf(ddk[j] - dkq + 1.f, 0.f);
            cyc += fabsf(Sij - Scol[j][il]);
        }
    }
    float contrib = cyc * (1.f/16256.f) + (float)(B_N - b) * tri * (1.f/32512.f);
    if (t < 16) contrib += (smrow[t] + cev[t]) * (1.f/16384.f);
    #pragma unroll
    for (int m = 32; m >= 1; m >>= 1) contrib += __shfl_xor(contrib, m, 64);
    if ((t & 63) == 0) wred[t >> 6] = contrib;
    __syncthreads();
    if (t == 0) {
        float tot = 0.f;
        #pragma unroll
        for (int w = 0; w < 8; ++w) tot += wred[w];
        atomicAdd(out, tot);
    }
}

extern "C" void kernel_launch(void* const* d_in, const int* in_sizes, int n_in,
                              void* d_out, int out_size, void* d_ws, size_t ws_size,
                              hipStream_t stream)
{
    const float* q  = (const float*)d_in[0];
    const float* kM = (const float*)d_in[1];
    const float* nM = (const float*)d_in[2];
    float* ws  = (float*)d_ws;
    float* out = (float*)d_out;

    k_gemm<<<B_N * KSPLIT, 512, 0, stream>>>(q, kM, nM, ws, out);
    k_fin2<<<B_N * 8, 512, 0, stream>>>(ws, out);
}